// Round 1
// baseline (7980.109 us; speedup 1.0000x reference)
//
#include <hip/hip_runtime.h>
#include <stdint.h>
#include <math.h>

#define NW      4096
#define TSTEPS  5722     // BURNIN + (512-1)*11 + 1
#define BURN    100
#define SSTRIDE 11
#define CH      1024     // proposal chunk size (LDS ring)
#define NTHR    256

struct K2 { uint32_t a, b; };

// Threefry-2x32, 20 rounds — matches jax._src.prng.threefry2x32 exactly.
__device__ __forceinline__ K2 tf(uint32_t k0, uint32_t k1, uint32_t c0, uint32_t c1) {
  uint32_t ks2 = k0 ^ k1 ^ 0x1BD11BDAu;
  uint32_t x0 = c0 + k0, x1 = c1 + k1;
#define RR(r) { x0 += x1; x1 = (x1 << (r)) | (x1 >> (32 - (r))); x1 ^= x0; }
  RR(13) RR(15) RR(26) RR(6)
  x0 += k1;  x1 += ks2 + 1u;
  RR(17) RR(29) RR(16) RR(24)
  x0 += ks2; x1 += k0 + 2u;
  RR(13) RR(15) RR(26) RR(6)
  x0 += k0;  x1 += k1 + 3u;
  RR(17) RR(29) RR(16) RR(24)
  x0 += k1;  x1 += ks2 + 4u;
  RR(13) RR(15) RR(26) RR(6)
  x0 += ks2; x1 += k0 + 5u;
#undef RR
  K2 r; r.a = x0; r.b = x1; return r;
}

// partitionable random_bits(key, 32, ()) == x0 ^ x1 of threefry(key, (0,0))
__device__ __forceinline__ uint32_t xbits(K2 k) {
  K2 r = tf(k.a, k.b, 0u, 0u);
  return r.a ^ r.b;
}

// jax.random.randint offset in [0, span): split key, draw hi/lo 32-bit words,
// offset = ((hi%span) * (2^32 % span) + lo%span) % span  (u32 wraparound math)
__device__ __forceinline__ uint32_t ri_off(K2 key, uint32_t span) {
  K2 k1 = tf(key.a, key.b, 0u, 0u);
  K2 k2 = tf(key.a, key.b, 0u, 1u);
  uint32_t hb = xbits(k1);
  uint32_t lb = xbits(k2);
  uint32_t m = 65536u % span;
  m = (m * m) % span;
  return ((hb % span) * m + (lb % span)) % span;
}

__global__ __launch_bounds__(NTHR)
void TwoOptMCMC_86148454023515_kernel(const float* __restrict__ bigram,
                                      const float* __restrict__ startw,
                                      const float* __restrict__ endw,
                                      int* __restrict__ out) {
  __shared__ uint32_t           s_perm[NW];     // 16 KB
  __shared__ unsigned long long s_comp[NW];     // 32 KB (low half reused as rotate tmp)
  __shared__ uint32_t           s_plohi[CH];    // 4 KB
  __shared__ uint32_t           s_psh[CH];      // 4 KB
  __shared__ float              s_plogu[CH];    // 4 KB
  __shared__ uint32_t           s_bc[4];

  uint32_t* s_tmp = (uint32_t*)s_comp;
  const int tid = threadIdx.x;

  // ---- base keys: jax.random.key(42) -> (0,42); kinit,kchain = split(key) ----
  K2 kinit  = tf(0u, 42u, 0u, 0u);
  K2 kchain = tf(0u, 42u, 0u, 1u);

  // ---- initial permutation: 2-round stable-sort shuffle (jax _shuffle) ----
  for (int i = tid; i < NW; i += NTHR) s_perm[i] = (uint32_t)i;
  __syncthreads();
  K2 kc = kinit;
  for (int rnd = 0; rnd < 2; ++rnd) {
    K2 knext = tf(kc.a, kc.b, 0u, 0u);   // key  = split(key)[0]
    K2 ksub  = tf(kc.a, kc.b, 0u, 1u);   // subkey = split(key)[1]
    for (int i = tid; i < NW; i += NTHR) {
      K2 r = tf(ksub.a, ksub.b, 0u, (uint32_t)i);
      uint32_t sk = r.a ^ r.b;           // partitionable random_bits element
      s_comp[i] = ((unsigned long long)sk << 24) |
                  ((unsigned long long)(uint32_t)i << 12) |
                  (unsigned long long)s_perm[i];
    }
    __syncthreads();
    // bitonic sort: unique composites (key, pos) => equals stable sort by key
    for (int k = 2; k <= NW; k <<= 1) {
      for (int j = k >> 1; j > 0; j >>= 1) {
        for (int i = tid; i < NW; i += NTHR) {
          int ixj = i ^ j;
          if (ixj > i) {
            unsigned long long va = s_comp[i], vb = s_comp[ixj];
            bool up = ((i & k) == 0);
            if ((va > vb) == up) { s_comp[i] = vb; s_comp[ixj] = va; }
          }
        }
        __syncthreads();
      }
    }
    for (int i = tid; i < NW; i += NTHR) s_perm[i] = (uint32_t)(s_comp[i] & 0xFFFull);
    __syncthreads();
    kc = knext;
  }

  // ---- MCMC chain ----
  for (int t0 = 0; t0 < TSTEPS; t0 += CH) {
    int nch = (TSTEPS - t0 < CH) ? (TSTEPS - t0) : CH;

    // proposals are state-independent: precompute chunk block-parallel
    for (int tt = tid; tt < nch; tt += NTHR) {
      int t = t0 + tt;
      K2 kt = tf(kchain.a, kchain.b, 0u, (uint32_t)t);  // keys[t] = split(kchain,T)[t]
      K2 kl = tf(kt.a, kt.b, 0u, 0u);
      K2 ka = tf(kt.a, kt.b, 0u, 1u);
      K2 kr = tf(kt.a, kt.b, 0u, 2u);
      K2 ku = tf(kt.a, kt.b, 0u, 3u);
      uint32_t l = 1u + ri_off(kl, 4095u);          // [1, 4095]
      uint32_t a = ri_off(ka, 4097u - l);           // [0, 4096-l]
      uint32_t b = a + l;
      uint32_t r = ri_off(kr, 4096u - l);           // [0, 4095-l]
      uint32_t c = (b + r + 1u) % 4097u;
      uint32_t lo, hi, sh;
      if (a < c) { lo = a; hi = c; sh = b - a; }
      else       { lo = c; hi = b; sh = a - c; }
      uint32_t ub = xbits(ku);
      float uf = __uint_as_float((ub >> 9) | 0x3F800000u) - 1.0f;
      float logu = (float)log((double)uf);          // uf==0 -> -inf -> accept
      s_plohi[tt] = lo | (hi << 16);
      s_psh[tt]   = sh;
      s_plogu[tt] = logu;
    }
    __syncthreads();

    for (int tt = 0; tt < nch; ++tt) {
      int t = t0 + tt;
      if (tid == 0) {
        uint32_t lohi = s_plohi[tt];
        uint32_t lo = lohi & 0xFFFFu, hi = lohi >> 16;
        uint32_t sh = s_psh[tt];
        float logu = s_plogu[tt];
        // 6-edge exact delta of the cyclic rotation move, in f64
        uint32_t pl   = s_perm[lo];
        uint32_t pls  = s_perm[lo + sh];
        uint32_t pls1 = s_perm[lo + sh - 1u];
        uint32_t ph1  = s_perm[hi - 1u];
        double d = (double)bigram[(size_t)ph1 * NW + pl]      // + new wrap edge
                 - (double)bigram[(size_t)pls1 * NW + pls];   // - broken internal edge
        if (lo > 0u) {
          uint32_t pm1 = s_perm[lo - 1u];
          d += (double)bigram[(size_t)pm1 * NW + pls]
             - (double)bigram[(size_t)pm1 * NW + pl];
        } else {
          d += (double)startw[pls] - (double)startw[pl];
        }
        if (hi < NW) {
          uint32_t ph = s_perm[hi];
          d += (double)bigram[(size_t)pls1 * NW + ph]
             - (double)bigram[(size_t)ph1 * NW + ph];
        } else {
          d += (double)endw[pls1] - (double)endw[ph1];
        }
        double mind = d < 0.0 ? d : 0.0;
        s_bc[0] = (mind > (double)logu) ? 1u : 0u;
        s_bc[1] = lo; s_bc[2] = hi; s_bc[3] = sh;
      }
      __syncthreads();
      uint32_t acc = s_bc[0], lo = s_bc[1], hi = s_bc[2], sh = s_bc[3];
      uint32_t span = hi - lo;
      if (acc) {
        for (uint32_t i = (uint32_t)tid; i < span; i += NTHR) {
          uint32_t idx = i + sh; if (idx >= span) idx -= span;
          s_tmp[i] = s_perm[lo + idx];
        }
        __syncthreads();
        for (uint32_t i = (uint32_t)tid; i < span; i += NTHR) s_perm[lo + i] = s_tmp[i];
        __syncthreads();
      }
      if (t >= BURN && ((t - BURN) % SSTRIDE) == 0) {
        int row = (t - BURN) / SSTRIDE;   // 0..511
        int* orow = out + (size_t)row * NW;
        for (int i = tid; i < NW; i += NTHR) orow[i] = (int)s_perm[i];
      }
      __syncthreads();   // protect s_bc / s_perm for next step
    }
  }
}

extern "C" void kernel_launch(void* const* d_in, const int* in_sizes, int n_in,
                              void* d_out, int out_size, void* d_ws, size_t ws_size,
                              hipStream_t stream) {
  (void)in_sizes; (void)n_in; (void)d_ws; (void)ws_size; (void)out_size;
  const float* bigram = (const float*)d_in[1];
  const float* startw = (const float*)d_in[2];
  const float* endw   = (const float*)d_in[3];
  int* out = (int*)d_out;
  hipLaunchKernelGGL(TwoOptMCMC_86148454023515_kernel, dim3(1), dim3(NTHR), 0, stream,
                     bigram, startw, endw, out);
}

// Round 2
// 6251.024 us; speedup vs baseline: 1.2766x; 1.2766x over previous
//
#include <hip/hip_runtime.h>
#include <stdint.h>
#include <math.h>

#define NW      4096
#define TSTEPS  5722     // BURNIN + (512-1)*11 + 1
#define BURN    100
#define SSTRIDE 11
#define CH      1024     // proposal chunk size
#define NTHR    256

struct K2 { uint32_t a, b; };

// Threefry-2x32, 20 rounds — matches jax._src.prng.threefry2x32 exactly.
__device__ __forceinline__ K2 tf(uint32_t k0, uint32_t k1, uint32_t c0, uint32_t c1) {
  uint32_t ks2 = k0 ^ k1 ^ 0x1BD11BDAu;
  uint32_t x0 = c0 + k0, x1 = c1 + k1;
#define RR(r) { x0 += x1; x1 = (x1 << (r)) | (x1 >> (32 - (r))); x1 ^= x0; }
  RR(13) RR(15) RR(26) RR(6)
  x0 += k1;  x1 += ks2 + 1u;
  RR(17) RR(29) RR(16) RR(24)
  x0 += ks2; x1 += k0 + 2u;
  RR(13) RR(15) RR(26) RR(6)
  x0 += k0;  x1 += k1 + 3u;
  RR(17) RR(29) RR(16) RR(24)
  x0 += k1;  x1 += ks2 + 4u;
  RR(13) RR(15) RR(26) RR(6)
  x0 += ks2; x1 += k0 + 5u;
#undef RR
  K2 r; r.a = x0; r.b = x1; return r;
}

__device__ __forceinline__ uint32_t xbits(K2 k) {
  K2 r = tf(k.a, k.b, 0u, 0u);
  return r.a ^ r.b;
}

__device__ __forceinline__ uint32_t ri_off(K2 key, uint32_t span) {
  K2 k1 = tf(key.a, key.b, 0u, 0u);
  K2 k2 = tf(key.a, key.b, 0u, 1u);
  uint32_t hb = xbits(k1);
  uint32_t lb = xbits(k2);
  uint32_t m = 65536u % span;
  m = (m * m) % span;
  return ((hb % span) * m + (lb % span)) % span;
}

// post-rotation source map: P_next[i] = P[smap(i)] when the move is accepted
__device__ __forceinline__ uint32_t smap(uint32_t i, uint32_t lo, uint32_t hi, uint32_t sh) {
  if (i >= lo && i < hi) {
    uint32_t s = hi - lo;
    uint32_t k = i - lo + sh;
    if (k >= s) k -= s;
    return lo + k;
  }
  return i;
}

// raw barrier: NO vmcnt drain (keeps speculative global loads in flight)
#define SYNC() do { asm volatile("s_waitcnt lgkmcnt(0)" ::: "memory"); \
                    __builtin_amdgcn_s_barrier(); } while (0)

__global__ __launch_bounds__(NTHR)
void TwoOptMCMC_86148454023515_kernel(const float* __restrict__ bigram,
                                      const float* __restrict__ startw,
                                      const float* __restrict__ endw,
                                      int* __restrict__ out) {
  __shared__ uint32_t           s_perm[NW];       // 16 KB
  __shared__ unsigned long long s_comp[NW];       // 32 KB (init sort only)
  __shared__ uint32_t           s_plohi[CH + 1];  // lo | hi<<16
  __shared__ uint32_t           s_psh[CH + 1];
  __shared__ float              s_plogu[CH + 1];
  __shared__ uint32_t           s_bc[2][4];       // double-buffered decision

  const int tid = threadIdx.x;

  // ---- base keys: jax.random.key(42) -> (0,42); kinit,kchain = split(key) ----
  K2 kinit  = tf(0u, 42u, 0u, 0u);
  K2 kchain = tf(0u, 42u, 0u, 1u);

  // ---- initial permutation: 2-round stable-sort shuffle (jax _shuffle) ----
  for (int i = tid; i < NW; i += NTHR) s_perm[i] = (uint32_t)i;
  __syncthreads();
  K2 kc = kinit;
  for (int rnd = 0; rnd < 2; ++rnd) {
    K2 knext = tf(kc.a, kc.b, 0u, 0u);
    K2 ksub  = tf(kc.a, kc.b, 0u, 1u);
    for (int i = tid; i < NW; i += NTHR) {
      K2 r = tf(ksub.a, ksub.b, 0u, (uint32_t)i);
      uint32_t sk = r.a ^ r.b;
      s_comp[i] = ((unsigned long long)sk << 24) |
                  ((unsigned long long)(uint32_t)i << 12) |
                  (unsigned long long)s_perm[i];
    }
    __syncthreads();
    for (int k = 2; k <= NW; k <<= 1) {
      for (int j = k >> 1; j > 0; j >>= 1) {
        for (int i = tid; i < NW; i += NTHR) {
          int ixj = i ^ j;
          if (ixj > i) {
            unsigned long long va = s_comp[i], vb = s_comp[ixj];
            bool up = ((i & k) == 0);
            if ((va > vb) == up) { s_comp[i] = vb; s_comp[ixj] = va; }
          }
        }
        __syncthreads();
      }
    }
    for (int i = tid; i < NW; i += NTHR) s_perm[i] = (uint32_t)(s_comp[i] & 0xFFFull);
    __syncthreads();
    kc = knext;
  }

  // ---- MCMC chain, 1-deep pipelined bigram loads ----
  float v0 = 0.f, v1 = 0.f, v2 = 0.f, v3 = 0.f, v4 = 0.f, v5 = 0.f; // tid0 pipeline regs
  int pend = -1;

  for (int t0 = 0; t0 < TSTEPS; t0 += CH) {
    int nch = (TSTEPS - t0 < CH) ? (TSTEPS - t0) : CH;

    // proposals for tt in [0, nch] (entry nch = lookahead into next chunk)
    for (int tt = tid; tt <= nch; tt += NTHR) {
      int t = t0 + tt;
      if (t < TSTEPS) {
        K2 kt = tf(kchain.a, kchain.b, 0u, (uint32_t)t);
        K2 kl = tf(kt.a, kt.b, 0u, 0u);
        K2 ka = tf(kt.a, kt.b, 0u, 1u);
        K2 kr = tf(kt.a, kt.b, 0u, 2u);
        K2 ku = tf(kt.a, kt.b, 0u, 3u);
        uint32_t l = 1u + ri_off(kl, 4095u);
        uint32_t a = ri_off(ka, 4097u - l);
        uint32_t b = a + l;
        uint32_t r = ri_off(kr, 4096u - l);
        uint32_t c = (b + r + 1u) % 4097u;
        uint32_t lo, hi, sh;
        if (a < c) { lo = a; hi = c; sh = b - a; }
        else       { lo = c; hi = b; sh = a - c; }
        uint32_t ub = xbits(ku);
        float uf = __uint_as_float((ub >> 9) | 0x3F800000u) - 1.0f;
        s_plohi[tt] = lo | (hi << 16);
        s_psh[tt]   = sh;
        s_plogu[tt] = (float)log((double)uf);
      }
    }
    SYNC();

    if (t0 == 0 && tid == 0) {
      // prologue: issue loads for step 0 from P_0
      uint32_t lohi2 = s_plohi[0];
      uint32_t lo2 = lohi2 & 0xFFFFu, hi2 = lohi2 >> 16, sh2 = s_psh[0];
      uint32_t pl   = s_perm[lo2];
      uint32_t pls  = s_perm[lo2 + sh2];
      uint32_t pls1 = s_perm[lo2 + sh2 - 1u];
      uint32_t ph1  = s_perm[hi2 - 1u];
      uint32_t pm1  = s_perm[(lo2 > 0u) ? lo2 - 1u : 0u];
      uint32_t ph   = s_perm[(hi2 < NW) ? hi2 : 0u];
      const float* a0 = bigram + (size_t)ph1 * NW + pl;
      const float* a1 = bigram + (size_t)pls1 * NW + pls;
      const float* a2 = (lo2 > 0u) ? bigram + (size_t)pm1 * NW + pls : startw + pls;
      const float* a3 = (lo2 > 0u) ? bigram + (size_t)pm1 * NW + pl  : startw + pl;
      const float* a4 = (hi2 < NW) ? bigram + (size_t)pls1 * NW + ph : endw + pls1;
      const float* a5 = (hi2 < NW) ? bigram + (size_t)ph1 * NW + ph  : endw + ph1;
      v0 = *a0; v1 = *a1; v2 = *a2; v3 = *a3; v4 = *a4; v5 = *a5;
    }

    for (int tt = 0; tt < nch; ++tt) {
      int t = t0 + tt;

      // emit previous sample (reads stable post-rotation s_perm) — all threads
      if (pend >= 0) {
        int* orow = out + (size_t)pend * NW;
        #pragma unroll
        for (int k = 0; k < 4; ++k) {
          int i = (k * NTHR + tid) * 4;
          uint4 w = *(const uint4*)&s_perm[i];
          *(uint4*)&orow[i] = w;
        }
      }

      if (tid == 0) {
        uint32_t lohi = s_plohi[tt];
        uint32_t lo = lohi & 0xFFFFu, hi = lohi >> 16, sh = s_psh[tt];
        float logu = s_plogu[tt];
        bool la = (t + 1 < TSTEPS);

        // speculative perm reads for step t+1 (both accept/reject variants),
        // issued BEFORE the vmcnt wait on v0..v5 so LDS latency overlaps.
        uint32_t lo2 = 0, hi2 = 1;
        uint32_t r0r=0,r1r=0,r2r=0,r3r=0,r4r=0,r5r=0;
        uint32_t r0a=0,r1a=0,r2a=0,r3a=0,r4a=0,r5a=0;
        if (la) {
          uint32_t lohi2 = s_plohi[tt + 1];
          lo2 = lohi2 & 0xFFFFu; hi2 = lohi2 >> 16;
          uint32_t sh2 = s_psh[tt + 1];
          uint32_t q0 = lo2;
          uint32_t q1 = lo2 + sh2;
          uint32_t q2 = lo2 + sh2 - 1u;
          uint32_t q3 = hi2 - 1u;
          uint32_t q4 = (lo2 > 0u) ? lo2 - 1u : 0u;
          uint32_t q5 = (hi2 < NW) ? hi2 : 0u;
          r0r = s_perm[q0]; r1r = s_perm[q1]; r2r = s_perm[q2];
          r3r = s_perm[q3]; r4r = s_perm[q4]; r5r = s_perm[q5];
          r0a = s_perm[smap(q0, lo, hi, sh)];
          r1a = s_perm[smap(q1, lo, hi, sh)];
          r2a = s_perm[smap(q2, lo, hi, sh)];
          r3a = s_perm[smap(q3, lo, hi, sh)];
          r4a = s_perm[smap(q4, lo, hi, sh)];
          r5a = s_perm[smap(q5, lo, hi, sh)];
        }

        // decision (vmcnt wait on v0..v5 happens here)
        double d = ((double)v0 - (double)v1);
        d += ((double)v2 - (double)v3);
        d += ((double)v4 - (double)v5);
        double mind = d < 0.0 ? d : 0.0;
        uint32_t acc = (mind > (double)logu) ? 1u : 0u;

        // select next-step values, form addresses, issue next loads
        if (la) {
          uint32_t pl   = acc ? r0a : r0r;
          uint32_t pls  = acc ? r1a : r1r;
          uint32_t pls1 = acc ? r2a : r2r;
          uint32_t ph1  = acc ? r3a : r3r;
          uint32_t pm1  = acc ? r4a : r4r;
          uint32_t ph   = acc ? r5a : r5r;
          const float* a0 = bigram + (size_t)ph1 * NW + pl;
          const float* a1 = bigram + (size_t)pls1 * NW + pls;
          const float* a2 = (lo2 > 0u) ? bigram + (size_t)pm1 * NW + pls : startw + pls;
          const float* a3 = (lo2 > 0u) ? bigram + (size_t)pm1 * NW + pl  : startw + pl;
          const float* a4 = (hi2 < NW) ? bigram + (size_t)pls1 * NW + ph : endw + pls1;
          const float* a5 = (hi2 < NW) ? bigram + (size_t)ph1 * NW + ph  : endw + ph1;
          v0 = *a0; v1 = *a1; v2 = *a2; v3 = *a3; v4 = *a4; v5 = *a5;
        }

        s_bc[t & 1][0] = acc;
        s_bc[t & 1][1] = lo;
        s_bc[t & 1][2] = hi;
        s_bc[t & 1][3] = sh;
      }

      pend = (t >= BURN && (t - BURN) % SSTRIDE == 0) ? (t - BURN) / SSTRIDE : -1;

      SYNC();  // release decision; no vmcnt drain
      uint32_t acc = s_bc[t & 1][0];
      if (acc) {
        uint32_t lo = s_bc[t & 1][1], hi = s_bc[t & 1][2], sh = s_bc[t & 1][3];
        uint32_t span = hi - lo;
        uint32_t rv[16];
        #pragma unroll
        for (int k = 0; k < 16; ++k) {
          uint32_t i = (uint32_t)tid + (uint32_t)k * NTHR;
          if (i < span) {
            uint32_t idx = i + sh; if (idx >= span) idx -= span;
            rv[k] = s_perm[lo + idx];
          }
        }
        SYNC();  // all reads done
        #pragma unroll
        for (int k = 0; k < 16; ++k) {
          uint32_t i = (uint32_t)tid + (uint32_t)k * NTHR;
          if (i < span) s_perm[lo + i] = rv[k];
        }
        SYNC();  // writes visible before next step's reads
      }
      // reject: no barrier needed — nothing wrote s_perm, s_bc is double-buffered
    }
  }

  // flush final sample
  if (pend >= 0) {
    int* orow = out + (size_t)pend * NW;
    #pragma unroll
    for (int k = 0; k < 4; ++k) {
      int i = (k * NTHR + tid) * 4;
      uint4 w = *(const uint4*)&s_perm[i];
      *(uint4*)&orow[i] = w;
    }
  }
}

extern "C" void kernel_launch(void* const* d_in, const int* in_sizes, int n_in,
                              void* d_out, int out_size, void* d_ws, size_t ws_size,
                              hipStream_t stream) {
  (void)in_sizes; (void)n_in; (void)d_ws; (void)ws_size; (void)out_size;
  const float* bigram = (const float*)d_in[1];
  const float* startw = (const float*)d_in[2];
  const float* endw   = (const float*)d_in[3];
  int* out = (int*)d_out;
  hipLaunchKernelGGL(TwoOptMCMC_86148454023515_kernel, dim3(1), dim3(NTHR), 0, stream,
                     bigram, startw, endw, out);
}